// Round 5
// baseline (793.242 us; speedup 1.0000x reference)
//
#include <hip/hip_runtime.h>
#include <hip/hip_bf16.h>

#define B_  512
#define D_  256
#define O_  256
#define H2_ 1024

typedef __attribute__((ext_vector_type(4))) float  f32x4;
typedef __attribute__((ext_vector_type(8))) short  short8;
typedef __attribute__((ext_vector_type(4))) short  short4v;

union S8u  { short4v v; unsigned u[2]; };
union S16u { short8  v; unsigned u[4]; };

// fp32 -> bf16 round-to-nearest-even on raw bits (finite inputs only)
__device__ __forceinline__ unsigned f32_bf16(float x) {
  unsigned u = __builtin_bit_cast(unsigned, x);
  return (u + 0x7fffu + ((u >> 16) & 1u)) >> 16;
}
__device__ __forceinline__ unsigned cvt_pk_bf16(float a, float b) {
  return f32_bf16(a) | (f32_bf16(b) << 16);
}

// async global->LDS, 16B per lane. LDS dest must be wave-uniform base + lane*16.
__device__ __forceinline__ void gl_lds16(const void* g, void* l) {
  __builtin_amdgcn_global_load_lds(
      (const __attribute__((address_space(1))) unsigned int*)g,
      (__attribute__((address_space(3))) unsigned int*)l, 16, 0, 0);
}

// ---------------------------------------------------------------------------
// W_d fp32 -> bf16 streaming convert (268 MB read, 134 MB write)
// ---------------------------------------------------------------------------
__global__ __launch_bounds__(256)
void wcvt(const float* __restrict__ src, ushort* __restrict__ dst, int n8) {
  int i = blockIdx.x * 256 + threadIdx.x;
  const int stride = gridDim.x * 256;
  for (; i < n8; i += stride) {
    const f32x4* p = (const f32x4*)(src + (size_t)i * 8);
    f32x4 a = p[0], b = p[1];
    S16u s;
    s.u[0] = cvt_pk_bf16(a.x, a.y);
    s.u[1] = cvt_pk_bf16(a.z, a.w);
    s.u[2] = cvt_pk_bf16(b.x, b.y);
    s.u[3] = cvt_pk_bf16(b.z, b.w);
    *(short8*)(dst + (size_t)i * 8) = s.v;
  }
}

// ---------------------------------------------------------------------------
// Generic small GEMM: C[M,N] = act(A[M,K] @ B[N,K]^T + bias[N]); fp32 in/out,
// bf16 MFMA inside. 64x64 tile per block, 256 threads = 4 waves.
// ---------------------------------------------------------------------------
template <int RELU>
__global__ __launch_bounds__(256)
void gemm_bt64(const float* __restrict__ A, const float* __restrict__ Bm,
               const float* __restrict__ bias, float* __restrict__ C,
               int M, int N, int K) {
  __shared__ __align__(16) short As[64][72];
  __shared__ __align__(16) short Bs[64][72];
  const int t    = threadIdx.x;
  const int m0   = blockIdx.y * 64;
  const int n0   = blockIdx.x * 64;
  const int f4c  = t & 15;
  const int rg   = t >> 4;
  const int lane = t & 63;
  const int w    = t >> 6;
  const int wm   = (w & 1) * 32;
  const int wn   = (w >> 1) * 32;
  const int lr   = lane & 15;
  const int lq   = lane >> 4;

  f32x4 acc[2][2];
  #pragma unroll
  for (int i = 0; i < 2; ++i)
    #pragma unroll
    for (int j = 0; j < 2; ++j) acc[i][j] = f32x4{0.f, 0.f, 0.f, 0.f};

  for (int k0 = 0; k0 < K; k0 += 64) {
    #pragma unroll
    for (int j = 0; j < 4; ++j) {
      int r = rg + 16 * j;
      f32x4 av = *(const f32x4*)(A  + (size_t)(m0 + r) * K + k0 + f4c * 4);
      f32x4 bv = *(const f32x4*)(Bm + (size_t)(n0 + r) * K + k0 + f4c * 4);
      S8u sa; sa.u[0] = cvt_pk_bf16(av.x, av.y); sa.u[1] = cvt_pk_bf16(av.z, av.w);
      S8u sb; sb.u[0] = cvt_pk_bf16(bv.x, bv.y); sb.u[1] = cvt_pk_bf16(bv.z, bv.w);
      *(short4v*)&As[r][f4c * 4] = sa.v;
      *(short4v*)&Bs[r][f4c * 4] = sb.v;
    }
    __syncthreads();
    #pragma unroll
    for (int ks = 0; ks < 2; ++ks) {
      short8 a0 = *(const short8*)&As[wm + lr     ][ks * 32 + lq * 8];
      short8 a1 = *(const short8*)&As[wm + 16 + lr][ks * 32 + lq * 8];
      short8 b0 = *(const short8*)&Bs[wn + lr     ][ks * 32 + lq * 8];
      short8 b1 = *(const short8*)&Bs[wn + 16 + lr][ks * 32 + lq * 8];
      acc[0][0] = __builtin_amdgcn_mfma_f32_16x16x32_bf16(a0, b0, acc[0][0], 0, 0, 0);
      acc[0][1] = __builtin_amdgcn_mfma_f32_16x16x32_bf16(a0, b1, acc[0][1], 0, 0, 0);
      acc[1][0] = __builtin_amdgcn_mfma_f32_16x16x32_bf16(a1, b0, acc[1][0], 0, 0, 0);
      acc[1][1] = __builtin_amdgcn_mfma_f32_16x16x32_bf16(a1, b1, acc[1][1], 0, 0, 0);
    }
    __syncthreads();
  }
  #pragma unroll
  for (int mi = 0; mi < 2; ++mi)
    #pragma unroll
    for (int ni = 0; ni < 2; ++ni)
      #pragma unroll
      for (int r = 0; r < 4; ++r) {
        int row = m0 + wm + mi * 16 + lq * 4 + r;
        int col = n0 + wn + ni * 16 + lr;
        float v = acc[mi][ni][r] + bias[col];
        if (RELU) v = fmaxf(v, 0.f);
        C[(size_t)row * N + col] = v;
      }
}

// ---------------------------------------------------------------------------
// out[b,o] += sum_d input[b,d] * b_d[d*O+o]
// ---------------------------------------------------------------------------
__global__ __launch_bounds__(256)
void bias_d_kernel(const float* __restrict__ inp, const float* __restrict__ b_d,
                   float* __restrict__ out) {
  const int b = blockIdx.x;
  const int o = threadIdx.x;
  const float* ir = inp + (size_t)b * D_;
  float s = 0.f;
  #pragma unroll 8
  for (int d = 0; d < D_; ++d)
    s += ir[d] * b_d[(size_t)d * O_ + o];
  out[(size_t)b * O_ + o] += s;
}

// ---------------------------------------------------------------------------
// Stage B v5: single-barrier double-buffered pipeline.
//   - B (bf16 W) double-buffered in LDS via async global_load_lds, XOR-swizzle
//   - A synthesized per-wave in REGISTERS from L2-resident x2 (no A LDS)
//   - per iter: barrier; issue next-iter B into buf[1-p]; compute from buf[p]
//     (async loads fly across the whole compute section before next drain)
// out[b,o] += sum_{d,h} (input[b,d]*x2[b,h]) * Wdb[(d*O+o), h]
// grid (8 tiles, 64 k-splits of 4 d); 128x128 C tile; 256 thr; LDS 32 KB.
// ---------------------------------------------------------------------------
__global__ __launch_bounds__(256)
void stage_b5(const float* __restrict__ x2, const float* __restrict__ inp,
              const ushort* __restrict__ Wdb, float* __restrict__ out) {
  __shared__ __align__(16) ushort Bb[2][128 * 64];
  const int t    = threadIdx.x;
  const int mt   = blockIdx.x >> 1;
  const int nt   = blockIdx.x & 1;
  const int d0   = blockIdx.y * 4;
  const int bm   = mt * 128;
  const int bn   = nt * 128;
  const int lane = t & 63;
  const int w    = t >> 6;
  const int wm   = (w & 1) * 64;
  const int wn   = (w >> 1) * 64;
  const int lr   = lane & 15;
  const int lq   = lane >> 4;
  // B staging: round r, thread t fills phys chunk r*256+t; logical row
  // n = r*32 + (t>>3), source chunk col kc = (t&7) ^ ((t>>3)&7).
  const int srow = t >> 3;
  const int skc  = (t & 7) ^ ((t >> 3) & 7);

  f32x4 acc[4][4];
  #pragma unroll
  for (int mi = 0; mi < 4; ++mi)
    #pragma unroll
    for (int ni = 0; ni < 4; ++ni) acc[mi][ni] = f32x4{0.f, 0.f, 0.f, 0.f};

  // prologue: stage iter 0 into buf 0
  {
    const ushort* wb = Wdb + ((size_t)d0 * O_ + bn) * H2_;
    #pragma unroll
    for (int r = 0; r < 4; ++r) {
      int n = r * 32 + srow;
      gl_lds16(wb + (size_t)n * H2_ + skc * 8, &Bb[0][(size_t)(r * 256 + t) * 8]);
    }
  }

  float insc[4];
  for (int it = 0; it < 64; ++it) {
    const int p  = it & 1;
    const int d  = d0 + (it >> 4);
    const int h0 = (it & 15) * 64;
    if ((it & 15) == 0) {          // wave-uniform branch, 4 L2-hit scalar loads
      #pragma unroll
      for (int mi = 0; mi < 4; ++mi)
        insc[mi] = inp[(size_t)(bm + wm + mi * 16 + lr) * D_ + d];
    }
    __syncthreads();               // drains buf[p] loads; ends reads of buf[1-p]
    if (it < 63) {                 // issue next-iter B into buf[1-p] (async)
      const int itn = it + 1;
      const int dn  = d0 + (itn >> 4);
      const int hn  = (itn & 15) * 64;
      const ushort* wbn = Wdb + ((size_t)dn * O_ + bn) * H2_;
      #pragma unroll
      for (int r = 0; r < 4; ++r) {
        int n = r * 32 + srow;
        gl_lds16(wbn + (size_t)n * H2_ + hn + skc * 8,
                 &Bb[1 - p][(size_t)(r * 256 + t) * 8]);
      }
    }
    #pragma unroll
    for (int ks = 0; ks < 2; ++ks) {
      short8 bfr[4];
      #pragma unroll
      for (int ni = 0; ni < 4; ++ni) {
        int n  = wn + ni * 16 + lr;
        int kc = (ks * 4 + lq) ^ (n & 7);
        bfr[ni] = *(const short8*)&Bb[p][(size_t)(n * 8 + kc) * 8];
      }
      #pragma unroll
      for (int mh = 0; mh < 2; ++mh) {   // mi pairs to cap VGPR pressure
        const int m0i = mh * 2;
        const float* xp0 = x2 + (size_t)(bm + wm + m0i * 16 + lr) * H2_ + h0 + ks * 32 + lq * 8;
        const float* xp1 = x2 + (size_t)(bm + wm + (m0i + 1) * 16 + lr) * H2_ + h0 + ks * 32 + lq * 8;
        f32x4 x0a = *(const f32x4*)xp0, x0b = *(const f32x4*)(xp0 + 4);
        f32x4 x1a = *(const f32x4*)xp1, x1b = *(const f32x4*)(xp1 + 4);
        float s0 = insc[m0i], s1 = insc[m0i + 1];
        S16u a0, a1;
        a0.u[0] = cvt_pk_bf16(x0a.x * s0, x0a.y * s0);
        a0.u[1] = cvt_pk_bf16(x0a.z * s0, x0a.w * s0);
        a0.u[2] = cvt_pk_bf16(x0b.x * s0, x0b.y * s0);
        a0.u[3] = cvt_pk_bf16(x0b.z * s0, x0b.w * s0);
        a1.u[0] = cvt_pk_bf16(x1a.x * s1, x1a.y * s1);
        a1.u[1] = cvt_pk_bf16(x1a.z * s1, x1a.w * s1);
        a1.u[2] = cvt_pk_bf16(x1b.x * s1, x1b.y * s1);
        a1.u[3] = cvt_pk_bf16(x1b.z * s1, x1b.w * s1);
        #pragma unroll
        for (int ni = 0; ni < 4; ++ni) {
          acc[m0i][ni]     = __builtin_amdgcn_mfma_f32_16x16x32_bf16(a0.v, bfr[ni], acc[m0i][ni],     0, 0, 0);
          acc[m0i + 1][ni] = __builtin_amdgcn_mfma_f32_16x16x32_bf16(a1.v, bfr[ni], acc[m0i + 1][ni], 0, 0, 0);
        }
      }
    }
  }

  #pragma unroll
  for (int mi = 0; mi < 4; ++mi)
    #pragma unroll
    for (int ni = 0; ni < 4; ++ni)
      #pragma unroll
      for (int r = 0; r < 4; ++r) {
        int row = bm + wm + mi * 16 + lq * 4 + r;
        int col = bn + wn + ni * 16 + lr;
        atomicAdd(out + (size_t)row * O_ + col, acc[mi][ni][r]);
      }
}

// ---------------------------------------------------------------------------
// Fallback stage B (fp32 W, proven round 2: 238 us) for small ws_size.
// ---------------------------------------------------------------------------
__global__ __launch_bounds__(256, 2)
void stage_b(const float* __restrict__ x2, const float* __restrict__ inp,
             const float* __restrict__ Wd, float* __restrict__ out) {
  __shared__ __align__(16) short As[128][72];
  __shared__ __align__(16) short Bs[128][72];
  const int t    = threadIdx.x;
  const int mt   = blockIdx.x >> 1;
  const int nt   = blockIdx.x & 1;
  const int d0   = blockIdx.y * 4;
  const int bm   = mt * 128;
  const int bn   = nt * 128;
  const int f4c  = t & 15;
  const int rg   = t >> 4;
  const int lane = t & 63;
  const int w    = t >> 6;
  const int wm   = (w & 1) * 64;
  const int wn   = (w >> 1) * 64;
  const int lr   = lane & 15;
  const int lq   = lane >> 4;

  f32x4 acc[4][4];
  #pragma unroll
  for (int mi = 0; mi < 4; ++mi)
    #pragma unroll
    for (int ni = 0; ni < 4; ++ni) acc[mi][ni] = f32x4{0.f, 0.f, 0.f, 0.f};

  for (int dl = 0; dl < 4; ++dl) {
    const int d = d0 + dl;
    float insc[8];
    #pragma unroll
    for (int j = 0; j < 8; ++j)
      insc[j] = inp[(size_t)(bm + rg + 16 * j) * D_ + d];
    const float* wbase = Wd + ((size_t)d * O_ + bn) * H2_;

    for (int h0 = 0; h0 < H2_; h0 += 64) {
      #pragma unroll
      for (int j = 0; j < 8; ++j) {
        int r = rg + 16 * j;
        f32x4 xv = *(const f32x4*)(x2 + (size_t)(bm + r) * H2_ + h0 + f4c * 4);
        float s = insc[j];
        S8u sa;
        sa.u[0] = cvt_pk_bf16(xv.x * s, xv.y * s);
        sa.u[1] = cvt_pk_bf16(xv.z * s, xv.w * s);
        *(short4v*)&As[r][f4c * 4] = sa.v;
        f32x4 wv = *(const f32x4*)(wbase + (size_t)r * H2_ + h0 + f4c * 4);
        S8u sb; sb.u[0] = cvt_pk_bf16(wv.x, wv.y); sb.u[1] = cvt_pk_bf16(wv.z, wv.w);
        *(short4v*)&Bs[r][f4c * 4] = sb.v;
      }
      __syncthreads();
      #pragma unroll
      for (int ks = 0; ks < 2; ++ks) {
        short8 af[4], bfr[4];
        #pragma unroll
        for (int mi = 0; mi < 4; ++mi)
          af[mi] = *(const short8*)&As[wm + mi * 16 + lr][ks * 32 + lq * 8];
        #pragma unroll
        for (int ni = 0; ni < 4; ++ni)
          bfr[ni] = *(const short8*)&Bs[wn + ni * 16 + lr][ks * 32 + lq * 8];
        #pragma unroll
        for (int mi = 0; mi < 4; ++mi)
          #pragma unroll
          for (int ni = 0; ni < 4; ++ni)
            acc[mi][ni] = __builtin_amdgcn_mfma_f32_16x16x32_bf16(af[mi], bfr[ni],
                                                                  acc[mi][ni], 0, 0, 0);
      }
      __syncthreads();
    }
  }

  #pragma unroll
  for (int mi = 0; mi < 4; ++mi)
    #pragma unroll
    for (int ni = 0; ni < 4; ++ni)
      #pragma unroll
      for (int r = 0; r < 4; ++r) {
        int row = bm + wm + mi * 16 + lq * 4 + r;
        int col = bn + wn + ni * 16 + lr;
        atomicAdd(out + (size_t)row * O_ + col, acc[mi][ni][r]);
      }
}

extern "C" void kernel_launch(void* const* d_in, const int* in_sizes, int n_in,
                              void* d_out, int out_size, void* d_ws, size_t ws_size,
                              hipStream_t stream) {
  const float* input = (const float*)d_in[0];
  const float* nanf  = (const float*)d_in[1];
  const float* W_in  = (const float*)d_in[3];
  const float* b_in  = (const float*)d_in[4];
  const float* W_h1  = (const float*)d_in[5];
  const float* b_h1  = (const float*)d_in[6];
  const float* W_h2  = (const float*)d_in[7];
  const float* b_h2  = (const float*)d_in[8];
  const float* W_d   = (const float*)d_in[9];
  const float* b_d   = (const float*)d_in[10];
  const float* W_b   = (const float*)d_in[11];
  const float* b_b   = (const float*)d_in[12];
  float* out = (float*)d_out;

  float* x0 = (float*)d_ws;          // [512,512]  1 MB
  float* x1 = x0 + 512 * 512;        // [512,1024] 2 MB
  float* x2 = x1 + 512 * 1024;       // [512,1024] 2 MB
  ushort* Wdb = (ushort*)(x2 + 512 * 1024);  // [65536,1024] bf16, 134 MB
  const size_t need = 5242880 + (size_t)65536 * 1024 * 2;
  const bool use_bf16_w = ws_size >= need;

  if (use_bf16_w)
    wcvt<<<8192, 256, 0, stream>>>(W_d, Wdb, 65536 * 1024 / 8);

  gemm_bt64<1><<<dim3(8, 8),  256, 0, stream>>>(nanf, W_in, b_in, x0, 512, 512, 256);
  gemm_bt64<1><<<dim3(16, 8), 256, 0, stream>>>(x0, W_h1, b_h1, x1, 512, 1024, 512);
  gemm_bt64<1><<<dim3(16, 8), 256, 0, stream>>>(x1, W_h2, b_h2, x2, 512, 1024, 1024);
  gemm_bt64<0><<<dim3(4, 8),  256, 0, stream>>>(x2, W_b, b_b, out, 512, 256, 1024);
  bias_d_kernel<<<512, 256, 0, stream>>>(input, b_d, out);

  if (use_bf16_w)
    stage_b5<<<dim3(8, 64), 256, 0, stream>>>(x2, input, Wdb, out);
  else
    stage_b<<<dim3(8, 64), 256, 0, stream>>>(x2, input, W_d, out);
}

// Round 6
// 640.843 us; speedup vs baseline: 1.2378x; 1.2378x over previous
//
#include <hip/hip_runtime.h>
#include <hip/hip_bf16.h>

#define B_  512
#define D_  256
#define O_  256
#define H2_ 1024

typedef __attribute__((ext_vector_type(4))) float    f32x4;
typedef __attribute__((ext_vector_type(8))) short    short8;
typedef __attribute__((ext_vector_type(4))) short    short4v;
typedef __attribute__((ext_vector_type(8))) _Float16 half8;

union S8u  { short4v v; unsigned u[2]; };
union H8u  { half8 v; short8 s; };

// fp32 -> bf16 round-to-nearest-even on raw bits (finite inputs only)
__device__ __forceinline__ unsigned f32_bf16(float x) {
  unsigned u = __builtin_bit_cast(unsigned, x);
  return (u + 0x7fffu + ((u >> 16) & 1u)) >> 16;
}
__device__ __forceinline__ unsigned cvt_pk_bf16(float a, float b) {
  return f32_bf16(a) | (f32_bf16(b) << 16);
}

// async global->LDS, 16B per lane. LDS dest must be wave-uniform base + lane*16.
__device__ __forceinline__ void gl_lds16(const void* g, void* l) {
  __builtin_amdgcn_global_load_lds(
      (const __attribute__((address_space(1))) unsigned int*)g,
      (__attribute__((address_space(3))) unsigned int*)l, 16, 0, 0);
}

// ---------------------------------------------------------------------------
// fp32 -> f16 streaming converts
// ---------------------------------------------------------------------------
__global__ __launch_bounds__(256)
void wcvt_h(const float* __restrict__ src, _Float16* __restrict__ dst, int n8) {
  int i = blockIdx.x * 256 + threadIdx.x;
  const int stride = gridDim.x * 256;
  for (; i < n8; i += stride) {
    const f32x4* p = (const f32x4*)(src + (size_t)i * 8);
    f32x4 a = p[0], b = p[1];
    half8 h;
    h[0] = (_Float16)a.x; h[1] = (_Float16)a.y; h[2] = (_Float16)a.z; h[3] = (_Float16)a.w;
    h[4] = (_Float16)b.x; h[5] = (_Float16)b.y; h[6] = (_Float16)b.z; h[7] = (_Float16)b.w;
    *(half8*)(dst + (size_t)i * 8) = h;
  }
}

// ---------------------------------------------------------------------------
// Generic small GEMM: C[M,N] = act(A[M,K] @ B[N,K]^T + bias[N]); fp32 in/out,
// bf16 MFMA inside. 64x64 tile per block, 256 threads = 4 waves.
// ---------------------------------------------------------------------------
template <int RELU>
__global__ __launch_bounds__(256)
void gemm_bt64(const float* __restrict__ A, const float* __restrict__ Bm,
               const float* __restrict__ bias, float* __restrict__ C,
               int M, int N, int K) {
  __shared__ __align__(16) short As[64][72];
  __shared__ __align__(16) short Bs[64][72];
  const int t    = threadIdx.x;
  const int m0   = blockIdx.y * 64;
  const int n0   = blockIdx.x * 64;
  const int f4c  = t & 15;
  const int rg   = t >> 4;
  const int lane = t & 63;
  const int w    = t >> 6;
  const int wm   = (w & 1) * 32;
  const int wn   = (w >> 1) * 32;
  const int lr   = lane & 15;
  const int lq   = lane >> 4;

  f32x4 acc[2][2];
  #pragma unroll
  for (int i = 0; i < 2; ++i)
    #pragma unroll
    for (int j = 0; j < 2; ++j) acc[i][j] = f32x4{0.f, 0.f, 0.f, 0.f};

  for (int k0 = 0; k0 < K; k0 += 64) {
    #pragma unroll
    for (int j = 0; j < 4; ++j) {
      int r = rg + 16 * j;
      f32x4 av = *(const f32x4*)(A  + (size_t)(m0 + r) * K + k0 + f4c * 4);
      f32x4 bv = *(const f32x4*)(Bm + (size_t)(n0 + r) * K + k0 + f4c * 4);
      S8u sa; sa.u[0] = cvt_pk_bf16(av.x, av.y); sa.u[1] = cvt_pk_bf16(av.z, av.w);
      S8u sb; sb.u[0] = cvt_pk_bf16(bv.x, bv.y); sb.u[1] = cvt_pk_bf16(bv.z, bv.w);
      *(short4v*)&As[r][f4c * 4] = sa.v;
      *(short4v*)&Bs[r][f4c * 4] = sb.v;
    }
    __syncthreads();
    #pragma unroll
    for (int ks = 0; ks < 2; ++ks) {
      short8 a0 = *(const short8*)&As[wm + lr     ][ks * 32 + lq * 8];
      short8 a1 = *(const short8*)&As[wm + 16 + lr][ks * 32 + lq * 8];
      short8 b0 = *(const short8*)&Bs[wn + lr     ][ks * 32 + lq * 8];
      short8 b1 = *(const short8*)&Bs[wn + 16 + lr][ks * 32 + lq * 8];
      acc[0][0] = __builtin_amdgcn_mfma_f32_16x16x32_bf16(a0, b0, acc[0][0], 0, 0, 0);
      acc[0][1] = __builtin_amdgcn_mfma_f32_16x16x32_bf16(a0, b1, acc[0][1], 0, 0, 0);
      acc[1][0] = __builtin_amdgcn_mfma_f32_16x16x32_bf16(a1, b0, acc[1][0], 0, 0, 0);
      acc[1][1] = __builtin_amdgcn_mfma_f32_16x16x32_bf16(a1, b1, acc[1][1], 0, 0, 0);
    }
    __syncthreads();
  }
  #pragma unroll
  for (int mi = 0; mi < 2; ++mi)
    #pragma unroll
    for (int ni = 0; ni < 2; ++ni)
      #pragma unroll
      for (int r = 0; r < 4; ++r) {
        int row = m0 + wm + mi * 16 + lq * 4 + r;
        int col = n0 + wn + ni * 16 + lr;
        float v = acc[mi][ni][r] + bias[col];
        if (RELU) v = fmaxf(v, 0.f);
        C[(size_t)row * N + col] = v;
      }
}

// ---------------------------------------------------------------------------
// out[b,o] += sum_d input[b,d] * b_d[d*O+o]
// ---------------------------------------------------------------------------
__global__ __launch_bounds__(256)
void bias_d_kernel(const float* __restrict__ inp, const float* __restrict__ b_d,
                   float* __restrict__ out) {
  const int b = blockIdx.x;
  const int o = threadIdx.x;
  const float* ir = inp + (size_t)b * D_;
  float s = 0.f;
  #pragma unroll 8
  for (int d = 0; d < D_; ++d)
    s += ir[d] * b_d[(size_t)d * O_ + o];
  out[(size_t)b * O_ + o] += s;
}

// ---------------------------------------------------------------------------
// Stage B v6: m97-shape K-loop, BOTH operands async-staged unscaled (f16),
// per-d scale applied as one broadcast v_pk_mul_f16 on the A fragment
// (A-layout: lane holds rows m = lane&15 only -> scale is one scalar/lane).
// out[b,o] += sum_{d,h} (input[b,d]*x2[b,h]) * Wd[(d*O+o), h]
// grid (8 tiles, 64 k-splits of 4 d); 128x128 C tile; LDS 32 KB.
// XOR-swizzled chunk layout for both tiles: phys(n,kc) = n*8 + (kc ^ (n&7)).
// ---------------------------------------------------------------------------
__global__ __launch_bounds__(256)
void stage_b6(const _Float16* __restrict__ x2h, const float* __restrict__ inp,
              const _Float16* __restrict__ Wdh, float* __restrict__ out) {
  __shared__ __align__(16) ushort As[128 * 64];
  __shared__ __align__(16) ushort Bs[128 * 64];
  const int t    = threadIdx.x;
  const int mt   = blockIdx.x >> 1;
  const int nt   = blockIdx.x & 1;
  const int d0   = blockIdx.y * 4;
  const int bm   = mt * 128;
  const int bn   = nt * 128;
  const int lane = t & 63;
  const int w    = t >> 6;
  const int wm   = (w & 1) * 64;
  const int wn   = (w >> 1) * 64;
  const int lr   = lane & 15;
  const int lq   = lane >> 4;
  // staging: round r, thread t fills phys chunk r*256+t; logical row
  // n = r*32 + (t>>3), source chunk col kc = (t&7) ^ ((t>>3)&7).
  const int srow = t >> 3;
  const int skc  = (t & 7) ^ ((t >> 3) & 7);

  f32x4 acc[4][4];
  #pragma unroll
  for (int mi = 0; mi < 4; ++mi)
    #pragma unroll
    for (int ni = 0; ni < 4; ++ni) acc[mi][ni] = f32x4{0.f, 0.f, 0.f, 0.f};

  const _Float16* xa = x2h + (size_t)bm * H2_;   // A source (d-invariant)

  for (int dl = 0; dl < 4; ++dl) {
    const int d = d0 + dl;
    const _Float16* wb = Wdh + ((size_t)d * O_ + bn) * H2_;
    // per-lane row scales: A-frag lane holds rows m = lane&15 of each 16-blk
    _Float16 hs[4];
    #pragma unroll
    for (int mi = 0; mi < 4; ++mi)
      hs[mi] = (_Float16)inp[(size_t)(bm + wm + mi * 16 + lr) * D_ + d];

    for (int h0 = 0; h0 < H2_; h0 += 64) {
      #pragma unroll
      for (int r = 0; r < 4; ++r) {
        int n = r * 32 + srow;
        gl_lds16(xa + (size_t)n * H2_ + h0 + skc * 8, &As[(size_t)(r * 256 + t) * 8]);
        gl_lds16(wb + (size_t)n * H2_ + h0 + skc * 8, &Bs[(size_t)(r * 256 + t) * 8]);
      }
      __syncthreads();  // drains vmcnt: DMA writes to LDS visible
      #pragma unroll
      for (int ks = 0; ks < 2; ++ks) {
        half8 af[4], bfr[4];
        #pragma unroll
        for (int mi = 0; mi < 4; ++mi) {
          int m  = wm + mi * 16 + lr;
          int kc = (ks * 4 + lq) ^ (lr & 7);
          af[mi] = *(const half8*)&As[(size_t)(m * 8 + kc) * 8];
        }
        #pragma unroll
        for (int ni = 0; ni < 4; ++ni) {
          int n  = wn + ni * 16 + lr;
          int kc = (ks * 4 + lq) ^ (lr & 7);
          bfr[ni] = *(const half8*)&Bs[(size_t)(n * 8 + kc) * 8];
        }
        #pragma unroll
        for (int mi = 0; mi < 4; ++mi) {
          half8 asb = af[mi] * hs[mi];   // 4x v_pk_mul_f16, broadcast scale
          #pragma unroll
          for (int ni = 0; ni < 4; ++ni)
            acc[mi][ni] = __builtin_amdgcn_mfma_f32_16x16x32_f16(asb, bfr[ni],
                                                                 acc[mi][ni], 0, 0, 0);
        }
      }
      __syncthreads();  // readers done before next iter's DMA overwrites
    }
  }

  #pragma unroll
  for (int mi = 0; mi < 4; ++mi)
    #pragma unroll
    for (int ni = 0; ni < 4; ++ni)
      #pragma unroll
      for (int r = 0; r < 4; ++r) {
        int row = bm + wm + mi * 16 + lq * 4 + r;
        int col = bn + wn + ni * 16 + lr;
        atomicAdd(out + (size_t)row * O_ + col, acc[mi][ni][r]);
      }
}

// ---------------------------------------------------------------------------
// Fallback stage B (fp32 W, proven round 2: 238 us) for small ws_size.
// ---------------------------------------------------------------------------
__global__ __launch_bounds__(256, 2)
void stage_b(const float* __restrict__ x2, const float* __restrict__ inp,
             const float* __restrict__ Wd, float* __restrict__ out) {
  __shared__ __align__(16) short As[128][72];
  __shared__ __align__(16) short Bs[128][72];
  const int t    = threadIdx.x;
  const int mt   = blockIdx.x >> 1;
  const int nt   = blockIdx.x & 1;
  const int d0   = blockIdx.y * 4;
  const int bm   = mt * 128;
  const int bn   = nt * 128;
  const int f4c  = t & 15;
  const int rg   = t >> 4;
  const int lane = t & 63;
  const int w    = t >> 6;
  const int wm   = (w & 1) * 64;
  const int wn   = (w >> 1) * 64;
  const int lr   = lane & 15;
  const int lq   = lane >> 4;

  f32x4 acc[4][4];
  #pragma unroll
  for (int mi = 0; mi < 4; ++mi)
    #pragma unroll
    for (int ni = 0; ni < 4; ++ni) acc[mi][ni] = f32x4{0.f, 0.f, 0.f, 0.f};

  for (int dl = 0; dl < 4; ++dl) {
    const int d = d0 + dl;
    float insc[8];
    #pragma unroll
    for (int j = 0; j < 8; ++j)
      insc[j] = inp[(size_t)(bm + rg + 16 * j) * D_ + d];
    const float* wbase = Wd + ((size_t)d * O_ + bn) * H2_;

    for (int h0 = 0; h0 < H2_; h0 += 64) {
      #pragma unroll
      for (int j = 0; j < 8; ++j) {
        int r = rg + 16 * j;
        f32x4 xv = *(const f32x4*)(x2 + (size_t)(bm + r) * H2_ + h0 + f4c * 4);
        float s = insc[j];
        S8u sa;
        sa.u[0] = cvt_pk_bf16(xv.x * s, xv.y * s);
        sa.u[1] = cvt_pk_bf16(xv.z * s, xv.w * s);
        *(short4v*)&As[r][f4c * 4] = sa.v;
        f32x4 wv = *(const f32x4*)(wbase + (size_t)r * H2_ + h0 + f4c * 4);
        S8u sb; sb.u[0] = cvt_pk_bf16(wv.x, wv.y); sb.u[1] = cvt_pk_bf16(wv.z, wv.w);
        *(short4v*)&Bs[r][f4c * 4] = sb.v;
      }
      __syncthreads();
      #pragma unroll
      for (int ks = 0; ks < 2; ++ks) {
        short8 af[4], bfr[4];
        #pragma unroll
        for (int mi = 0; mi < 4; ++mi)
          af[mi] = *(const short8*)&As[wm + mi * 16 + lr][ks * 32 + lq * 8];
        #pragma unroll
        for (int ni = 0; ni < 4; ++ni)
          bfr[ni] = *(const short8*)&Bs[wn + ni * 16 + lr][ks * 32 + lq * 8];
        #pragma unroll
        for (int mi = 0; mi < 4; ++mi)
          #pragma unroll
          for (int ni = 0; ni < 4; ++ni)
            acc[mi][ni] = __builtin_amdgcn_mfma_f32_16x16x32_bf16(af[mi], bfr[ni],
                                                                  acc[mi][ni], 0, 0, 0);
      }
      __syncthreads();
    }
  }

  #pragma unroll
  for (int mi = 0; mi < 4; ++mi)
    #pragma unroll
    for (int ni = 0; ni < 4; ++ni)
      #pragma unroll
      for (int r = 0; r < 4; ++r) {
        int row = bm + wm + mi * 16 + lq * 4 + r;
        int col = bn + wn + ni * 16 + lr;
        atomicAdd(out + (size_t)row * O_ + col, acc[mi][ni][r]);
      }
}

extern "C" void kernel_launch(void* const* d_in, const int* in_sizes, int n_in,
                              void* d_out, int out_size, void* d_ws, size_t ws_size,
                              hipStream_t stream) {
  const float* input = (const float*)d_in[0];
  const float* nanf  = (const float*)d_in[1];
  const float* W_in  = (const float*)d_in[3];
  const float* b_in  = (const float*)d_in[4];
  const float* W_h1  = (const float*)d_in[5];
  const float* b_h1  = (const float*)d_in[6];
  const float* W_h2  = (const float*)d_in[7];
  const float* b_h2  = (const float*)d_in[8];
  const float* W_d   = (const float*)d_in[9];
  const float* b_d   = (const float*)d_in[10];
  const float* W_b   = (const float*)d_in[11];
  const float* b_b   = (const float*)d_in[12];
  float* out = (float*)d_out;

  float* x0 = (float*)d_ws;            // [512,512]  1 MB
  float* x1 = x0 + 512 * 512;          // [512,1024] 2 MB
  float* x2 = x1 + 512 * 1024;         // [512,1024] 2 MB
  _Float16* Wdh = (_Float16*)(x2 + 512 * 1024);     // [65536,1024] f16, 134 MB
  _Float16* x2h = Wdh + (size_t)65536 * 1024;       // [512,1024]   f16,   1 MB
  const size_t need = 5242880 + ((size_t)65536 * 1024 + 512 * 1024) * 2;
  const bool use_f16 = ws_size >= need;

  if (use_f16)
    wcvt_h<<<8192, 256, 0, stream>>>(W_d, Wdh, 65536 * 1024 / 8);

  gemm_bt64<1><<<dim3(8, 8),  256, 0, stream>>>(nanf, W_in, b_in, x0, 512, 512, 256);
  gemm_bt64<1><<<dim3(16, 8), 256, 0, stream>>>(x0, W_h1, b_h1, x1, 512, 1024, 512);
  gemm_bt64<1><<<dim3(16, 8), 256, 0, stream>>>(x1, W_h2, b_h2, x2, 512, 1024, 1024);
  gemm_bt64<0><<<dim3(4, 8),  256, 0, stream>>>(x2, W_b, b_b, out, 512, 256, 1024);
  bias_d_kernel<<<512, 256, 0, stream>>>(input, b_d, out);

  if (use_f16) {
    wcvt_h<<<256, 256, 0, stream>>>(x2, x2h, 512 * 1024 / 8);
    stage_b6<<<dim3(8, 64), 256, 0, stream>>>(x2h, input, Wdh, out);
  } else {
    stage_b<<<dim3(8, 64), 256, 0, stream>>>(x2, input, W_d, out);
  }
}

// Round 7
// 637.649 us; speedup vs baseline: 1.2440x; 1.0050x over previous
//
#include <hip/hip_runtime.h>
#include <hip/hip_bf16.h>

#define B_  512
#define D_  256
#define O_  256
#define H2_ 1024

typedef __attribute__((ext_vector_type(4))) float    f32x4;
typedef __attribute__((ext_vector_type(8))) short    short8;
typedef __attribute__((ext_vector_type(4))) short    short4v;
typedef __attribute__((ext_vector_type(8))) _Float16 half8;

union S8u  { short4v v; unsigned u[2]; };

// fp32 -> bf16 round-to-nearest-even on raw bits (finite inputs only)
__device__ __forceinline__ unsigned f32_bf16(float x) {
  unsigned u = __builtin_bit_cast(unsigned, x);
  return (u + 0x7fffu + ((u >> 16) & 1u)) >> 16;
}
__device__ __forceinline__ unsigned cvt_pk_bf16(float a, float b) {
  return f32_bf16(a) | (f32_bf16(b) << 16);
}

// async global->LDS, 16B per lane. LDS dest must be wave-uniform base + lane*16.
__device__ __forceinline__ void gl_lds16(const void* g, void* l) {
  __builtin_amdgcn_global_load_lds(
      (const __attribute__((address_space(1))) unsigned int*)g,
      (__attribute__((address_space(3))) unsigned int*)l, 16, 0, 0);
}

// ---------------------------------------------------------------------------
// fp32 -> f16 streaming convert
// ---------------------------------------------------------------------------
__global__ __launch_bounds__(256)
void wcvt_h(const float* __restrict__ src, _Float16* __restrict__ dst, int n8) {
  int i = blockIdx.x * 256 + threadIdx.x;
  const int stride = gridDim.x * 256;
  for (; i < n8; i += stride) {
    const f32x4* p = (const f32x4*)(src + (size_t)i * 8);
    f32x4 a = p[0], b = p[1];
    half8 h;
    h[0] = (_Float16)a.x; h[1] = (_Float16)a.y; h[2] = (_Float16)a.z; h[3] = (_Float16)a.w;
    h[4] = (_Float16)b.x; h[5] = (_Float16)b.y; h[6] = (_Float16)b.z; h[7] = (_Float16)b.w;
    *(half8*)(dst + (size_t)i * 8) = h;
  }
}

// ---------------------------------------------------------------------------
// Generic small GEMM: C[M,N] = act(A[M,K] @ B[N,K]^T + bias[N]); fp32 in/out,
// bf16 MFMA inside. 64x64 tile per block, 256 threads = 4 waves.
// ---------------------------------------------------------------------------
template <int RELU>
__global__ __launch_bounds__(256)
void gemm_bt64(const float* __restrict__ A, const float* __restrict__ Bm,
               const float* __restrict__ bias, float* __restrict__ C,
               int M, int N, int K) {
  __shared__ __align__(16) short As[64][72];
  __shared__ __align__(16) short Bs[64][72];
  const int t    = threadIdx.x;
  const int m0   = blockIdx.y * 64;
  const int n0   = blockIdx.x * 64;
  const int f4c  = t & 15;
  const int rg   = t >> 4;
  const int lane = t & 63;
  const int w    = t >> 6;
  const int wm   = (w & 1) * 32;
  const int wn   = (w >> 1) * 32;
  const int lr   = lane & 15;
  const int lq   = lane >> 4;

  f32x4 acc[2][2];
  #pragma unroll
  for (int i = 0; i < 2; ++i)
    #pragma unroll
    for (int j = 0; j < 2; ++j) acc[i][j] = f32x4{0.f, 0.f, 0.f, 0.f};

  for (int k0 = 0; k0 < K; k0 += 64) {
    #pragma unroll
    for (int j = 0; j < 4; ++j) {
      int r = rg + 16 * j;
      f32x4 av = *(const f32x4*)(A  + (size_t)(m0 + r) * K + k0 + f4c * 4);
      f32x4 bv = *(const f32x4*)(Bm + (size_t)(n0 + r) * K + k0 + f4c * 4);
      S8u sa; sa.u[0] = cvt_pk_bf16(av.x, av.y); sa.u[1] = cvt_pk_bf16(av.z, av.w);
      S8u sb; sb.u[0] = cvt_pk_bf16(bv.x, bv.y); sb.u[1] = cvt_pk_bf16(bv.z, bv.w);
      *(short4v*)&As[r][f4c * 4] = sa.v;
      *(short4v*)&Bs[r][f4c * 4] = sb.v;
    }
    __syncthreads();
    #pragma unroll
    for (int ks = 0; ks < 2; ++ks) {
      short8 a0 = *(const short8*)&As[wm + lr     ][ks * 32 + lq * 8];
      short8 a1 = *(const short8*)&As[wm + 16 + lr][ks * 32 + lq * 8];
      short8 b0 = *(const short8*)&Bs[wn + lr     ][ks * 32 + lq * 8];
      short8 b1 = *(const short8*)&Bs[wn + 16 + lr][ks * 32 + lq * 8];
      acc[0][0] = __builtin_amdgcn_mfma_f32_16x16x32_bf16(a0, b0, acc[0][0], 0, 0, 0);
      acc[0][1] = __builtin_amdgcn_mfma_f32_16x16x32_bf16(a0, b1, acc[0][1], 0, 0, 0);
      acc[1][0] = __builtin_amdgcn_mfma_f32_16x16x32_bf16(a1, b0, acc[1][0], 0, 0, 0);
      acc[1][1] = __builtin_amdgcn_mfma_f32_16x16x32_bf16(a1, b1, acc[1][1], 0, 0, 0);
    }
    __syncthreads();
  }
  #pragma unroll
  for (int mi = 0; mi < 2; ++mi)
    #pragma unroll
    for (int ni = 0; ni < 2; ++ni)
      #pragma unroll
      for (int r = 0; r < 4; ++r) {
        int row = m0 + wm + mi * 16 + lq * 4 + r;
        int col = n0 + wn + ni * 16 + lr;
        float v = acc[mi][ni][r] + bias[col];
        if (RELU) v = fmaxf(v, 0.f);
        C[(size_t)row * N + col] = v;
      }
}

// ---------------------------------------------------------------------------
// out[b,o] += sum_d input[b,d] * b_d[d*O+o]
// ---------------------------------------------------------------------------
__global__ __launch_bounds__(256)
void bias_d_kernel(const float* __restrict__ inp, const float* __restrict__ b_d,
                   float* __restrict__ out) {
  const int b = blockIdx.x;
  const int o = threadIdx.x;
  const float* ir = inp + (size_t)b * D_;
  float s = 0.f;
  #pragma unroll 8
  for (int d = 0; d < D_; ++d)
    s += ir[d] * b_d[(size_t)d * O_ + o];
  out[(size_t)b * O_ + o] += s;
}

// ---------------------------------------------------------------------------
// Stage B v7: SINGLE-barrier double-buffered pipeline, both operands DMA'd.
//   per iter: barrier (drains DMA issued one full compute-section ago);
//             issue next-iter A+B DMA into buf[1-p]; ds_read+MFMA from buf[p].
//   A staged UNSCALED; per-d scale = one broadcast v_pk_mul_f16 per A-frag
//   (A-layout: lane holds rows m=lane&15 only). Round-5 lesson: A must come
//   from LDS, not global, inside the compute section.
// out[b,o] += sum_{d,h} (input[b,d]*x2[b,h]) * Wdh[(d*O+o), h]
// grid (8 tiles, 64 k-splits of 4 d) = 512 blocks = exactly 2/CU (LDS 64 KB).
// XOR-swizzled chunk layout both tiles: phys(n,kc) = n*8 + (kc ^ (n&7)).
// ---------------------------------------------------------------------------
__global__ __launch_bounds__(256)
void stage_b7(const _Float16* __restrict__ x2h, const float* __restrict__ inp,
              const _Float16* __restrict__ Wdh, float* __restrict__ out) {
  __shared__ __align__(16) ushort As[2][128 * 64];
  __shared__ __align__(16) ushort Bs[2][128 * 64];
  const int t    = threadIdx.x;
  const int mt   = blockIdx.x >> 1;
  const int nt   = blockIdx.x & 1;
  const int d0   = blockIdx.y * 4;
  const int bm   = mt * 128;
  const int bn   = nt * 128;
  const int lane = t & 63;
  const int w    = t >> 6;
  const int wm   = (w & 1) * 64;
  const int wn   = (w >> 1) * 64;
  const int lr   = lane & 15;
  const int lq   = lane >> 4;
  // staging: round r, thread t fills phys chunk r*256+t; logical row
  // n = r*32 + (t>>3), source chunk col kc = (t&7) ^ ((t>>3)&7).
  const int srow = t >> 3;
  const int skc  = (t & 7) ^ ((t >> 3) & 7);

  f32x4 acc[4][4];
  #pragma unroll
  for (int mi = 0; mi < 4; ++mi)
    #pragma unroll
    for (int ni = 0; ni < 4; ++ni) acc[mi][ni] = f32x4{0.f, 0.f, 0.f, 0.f};

  const _Float16* xa = x2h + (size_t)bm * H2_;

  // prologue: stage iter 0 (d=d0, h0=0) into buf 0
  {
    const _Float16* wb = Wdh + ((size_t)d0 * O_ + bn) * H2_;
    #pragma unroll
    for (int r = 0; r < 4; ++r) {
      int n = r * 32 + srow;
      gl_lds16(xa + (size_t)n * H2_ + skc * 8, &As[0][(size_t)(r * 256 + t) * 8]);
      gl_lds16(wb + (size_t)n * H2_ + skc * 8, &Bs[0][(size_t)(r * 256 + t) * 8]);
    }
  }

  _Float16 hs[4];
  for (int it = 0; it < 64; ++it) {
    const int p  = it & 1;
    if ((it & 15) == 0) {            // wave-uniform: per-d row scales (L2-hit)
      const int d = d0 + (it >> 4);
      #pragma unroll
      for (int mi = 0; mi < 4; ++mi)
        hs[mi] = (_Float16)inp[(size_t)(bm + wm + mi * 16 + lr) * D_ + d];
    }
    __syncthreads();                 // drains buf[p] DMA (issued last iter)
    if (it < 63) {                   // issue next-iter A+B into buf[1-p]
      const int itn = it + 1;
      const int dn  = d0 + (itn >> 4);
      const int hn  = (itn & 15) * 64;
      const _Float16* wbn = Wdh + ((size_t)dn * O_ + bn) * H2_;
      #pragma unroll
      for (int r = 0; r < 4; ++r) {
        int n = r * 32 + srow;
        gl_lds16(xa  + (size_t)n * H2_ + hn + skc * 8,
                 &As[1 - p][(size_t)(r * 256 + t) * 8]);
        gl_lds16(wbn + (size_t)n * H2_ + hn + skc * 8,
                 &Bs[1 - p][(size_t)(r * 256 + t) * 8]);
      }
    }
    #pragma unroll
    for (int ks = 0; ks < 2; ++ks) {
      half8 af[4], bfr[4];
      #pragma unroll
      for (int mi = 0; mi < 4; ++mi) {
        int m  = wm + mi * 16 + lr;
        int kc = (ks * 4 + lq) ^ (lr & 7);
        af[mi] = *(const half8*)&As[p][(size_t)(m * 8 + kc) * 8];
      }
      #pragma unroll
      for (int ni = 0; ni < 4; ++ni) {
        int n  = wn + ni * 16 + lr;
        int kc = (ks * 4 + lq) ^ (lr & 7);
        bfr[ni] = *(const half8*)&Bs[p][(size_t)(n * 8 + kc) * 8];
      }
      #pragma unroll
      for (int mi = 0; mi < 4; ++mi) {
        half8 asb = af[mi] * hs[mi];   // 4x v_pk_mul_f16, broadcast scale
        #pragma unroll
        for (int ni = 0; ni < 4; ++ni)
          acc[mi][ni] = __builtin_amdgcn_mfma_f32_16x16x32_f16(asb, bfr[ni],
                                                               acc[mi][ni], 0, 0, 0);
      }
    }
  }

  #pragma unroll
  for (int mi = 0; mi < 4; ++mi)
    #pragma unroll
    for (int ni = 0; ni < 4; ++ni)
      #pragma unroll
      for (int r = 0; r < 4; ++r) {
        int row = bm + wm + mi * 16 + lq * 4 + r;
        int col = bn + wn + ni * 16 + lr;
        atomicAdd(out + (size_t)row * O_ + col, acc[mi][ni][r]);
      }
}

// ---------------------------------------------------------------------------
// Fallback stage B (fp32 W, proven round 2: 238 us) for small ws_size.
// ---------------------------------------------------------------------------
__global__ __launch_bounds__(256, 2)
void stage_b(const float* __restrict__ x2, const float* __restrict__ inp,
             const float* __restrict__ Wd, float* __restrict__ out) {
  __shared__ __align__(16) short As[128][72];
  __shared__ __align__(16) short Bs[128][72];
  const int t    = threadIdx.x;
  const int mt   = blockIdx.x >> 1;
  const int nt   = blockIdx.x & 1;
  const int d0   = blockIdx.y * 4;
  const int bm   = mt * 128;
  const int bn   = nt * 128;
  const int f4c  = t & 15;
  const int rg   = t >> 4;
  const int lane = t & 63;
  const int w    = t >> 6;
  const int wm   = (w & 1) * 64;
  const int wn   = (w >> 1) * 64;
  const int lr   = lane & 15;
  const int lq   = lane >> 4;

  f32x4 acc[4][4];
  #pragma unroll
  for (int mi = 0; mi < 4; ++mi)
    #pragma unroll
    for (int ni = 0; ni < 4; ++ni) acc[mi][ni] = f32x4{0.f, 0.f, 0.f, 0.f};

  for (int dl = 0; dl < 4; ++dl) {
    const int d = d0 + dl;
    float insc[8];
    #pragma unroll
    for (int j = 0; j < 8; ++j)
      insc[j] = inp[(size_t)(bm + rg + 16 * j) * D_ + d];
    const float* wbase = Wd + ((size_t)d * O_ + bn) * H2_;

    for (int h0 = 0; h0 < H2_; h0 += 64) {
      #pragma unroll
      for (int j = 0; j < 8; ++j) {
        int r = rg + 16 * j;
        f32x4 xv = *(const f32x4*)(x2 + (size_t)(bm + r) * H2_ + h0 + f4c * 4);
        float s = insc[j];
        S8u sa;
        sa.u[0] = cvt_pk_bf16(xv.x * s, xv.y * s);
        sa.u[1] = cvt_pk_bf16(xv.z * s, xv.w * s);
        *(short4v*)&As[r][f4c * 4] = sa.v;
        f32x4 wv = *(const f32x4*)(wbase + (size_t)r * H2_ + h0 + f4c * 4);
        S8u sb; sb.u[0] = cvt_pk_bf16(wv.x, wv.y); sb.u[1] = cvt_pk_bf16(wv.z, wv.w);
        *(short4v*)&Bs[r][f4c * 4] = sb.v;
      }
      __syncthreads();
      #pragma unroll
      for (int ks = 0; ks < 2; ++ks) {
        short8 af[4], bfr[4];
        #pragma unroll
        for (int mi = 0; mi < 4; ++mi)
          af[mi] = *(const short8*)&As[wm + mi * 16 + lr][ks * 32 + lq * 8];
        #pragma unroll
        for (int ni = 0; ni < 4; ++ni)
          bfr[ni] = *(const short8*)&Bs[wn + ni * 16 + lr][ks * 32 + lq * 8];
        #pragma unroll
        for (int mi = 0; mi < 4; ++mi)
          #pragma unroll
          for (int ni = 0; ni < 4; ++ni)
            acc[mi][ni] = __builtin_amdgcn_mfma_f32_16x16x32_bf16(af[mi], bfr[ni],
                                                                  acc[mi][ni], 0, 0, 0);
      }
      __syncthreads();
    }
  }

  #pragma unroll
  for (int mi = 0; mi < 4; ++mi)
    #pragma unroll
    for (int ni = 0; ni < 4; ++ni)
      #pragma unroll
      for (int r = 0; r < 4; ++r) {
        int row = bm + wm + mi * 16 + lq * 4 + r;
        int col = bn + wn + ni * 16 + lr;
        atomicAdd(out + (size_t)row * O_ + col, acc[mi][ni][r]);
      }
}

extern "C" void kernel_launch(void* const* d_in, const int* in_sizes, int n_in,
                              void* d_out, int out_size, void* d_ws, size_t ws_size,
                              hipStream_t stream) {
  const float* input = (const float*)d_in[0];
  const float* nanf  = (const float*)d_in[1];
  const float* W_in  = (const float*)d_in[3];
  const float* b_in  = (const float*)d_in[4];
  const float* W_h1  = (const float*)d_in[5];
  const float* b_h1  = (const float*)d_in[6];
  const float* W_h2  = (const float*)d_in[7];
  const float* b_h2  = (const float*)d_in[8];
  const float* W_d   = (const float*)d_in[9];
  const float* b_d   = (const float*)d_in[10];
  const float* W_b   = (const float*)d_in[11];
  const float* b_b   = (const float*)d_in[12];
  float* out = (float*)d_out;

  float* x0 = (float*)d_ws;            // [512,512]  1 MB
  float* x1 = x0 + 512 * 512;          // [512,1024] 2 MB
  float* x2 = x1 + 512 * 1024;         // [512,1024] 2 MB
  _Float16* Wdh = (_Float16*)(x2 + 512 * 1024);     // [65536,1024] f16, 134 MB
  _Float16* x2h = Wdh + (size_t)65536 * 1024;       // [512,1024]   f16,   1 MB
  const size_t need = 5242880 + ((size_t)65536 * 1024 + 512 * 1024) * 2;
  const bool use_f16 = ws_size >= need;

  if (use_f16)
    wcvt_h<<<8192, 256, 0, stream>>>(W_d, Wdh, 65536 * 1024 / 8);

  gemm_bt64<1><<<dim3(8, 8),  256, 0, stream>>>(nanf, W_in, b_in, x0, 512, 512, 256);
  gemm_bt64<1><<<dim3(16, 8), 256, 0, stream>>>(x0, W_h1, b_h1, x1, 512, 1024, 512);
  gemm_bt64<1><<<dim3(16, 8), 256, 0, stream>>>(x1, W_h2, b_h2, x2, 512, 1024, 1024);
  gemm_bt64<0><<<dim3(4, 8),  256, 0, stream>>>(x2, W_b, b_b, out, 512, 256, 1024);
  bias_d_kernel<<<512, 256, 0, stream>>>(input, b_d, out);

  if (use_f16) {
    wcvt_h<<<256, 256, 0, stream>>>(x2, x2h, 512 * 1024 / 8);
    stage_b7<<<dim3(8, 64), 256, 0, stream>>>(x2h, input, Wdh, out);
  } else {
    stage_b<<<dim3(8, 64), 256, 0, stream>>>(x2, input, W_d, out);
  }
}